// Round 4
// baseline (651.464 us; speedup 1.0000x reference)
//
#include <hip/hip_runtime.h>

// ---------------------------------------------------------------------------
// CustomizedMultiHeadAttention: B=4 S=2048 D=1024 H=16 DH=64
// out [B,S,D] f32  +  attn_weights [B,H,S,S] f32, concat in d_out.
// v4: base-2 fixed-shift softmax (no max tracking; Q pre-scaled by
//     0.125*log2e), attn = exp2(s - c) with c = log2(sum exp2(s)) from a
//     separate pass1 kernel (KBLK=128, 32KB LDS). Pass2 stores normalized
//     weights directly; ctx needs no final normalization.
// ---------------------------------------------------------------------------

typedef unsigned short u16;
typedef unsigned int   u32;
typedef u16   u16x4  __attribute__((ext_vector_type(4)));
typedef u16   u16x8  __attribute__((ext_vector_type(8)));
typedef int   i32x4  __attribute__((ext_vector_type(4)));
typedef float f32x4  __attribute__((ext_vector_type(4)));
typedef __bf16 bf16x8 __attribute__((ext_vector_type(8)));

#define GLDS16(gp, lp)                                                         \
  __builtin_amdgcn_global_load_lds(                                            \
      (const __attribute__((address_space(1))) void*)(gp),                     \
      (__attribute__((address_space(3))) void*)(lp), 16, 0, 0)

__device__ __forceinline__ u16 f2bf(float x) {
  __bf16 h = (__bf16)x;
  union { __bf16 h; u16 u; } c; c.h = h; return c.u;
}

static const int Bn = 4, Sn = 2048, Dn = 1024, Hn = 16, DHn = 64;
#define MASK_NEG (-1442695.0f)   /* -1e6 * log2(e) */

// ------------------------------------------------- fused cast q,k,v f32->bf16
__global__ __launch_bounds__(256) void cast3_k(const float* __restrict__ q,
                                               const float* __restrict__ k,
                                               const float* __restrict__ v,
                                               u16* __restrict__ out) {
  int which = blockIdx.x >> 12;
  size_t li = (size_t)(blockIdx.x & 4095) * 256 + threadIdx.x;
  const float* src = which == 0 ? q : which == 1 ? k : v;
  const f32x4* p = (const f32x4*)src + li * 2;
  f32x4 a = p[0], b = p[1];
  u16x8 r;
  r[0]=f2bf(a[0]); r[1]=f2bf(a[1]); r[2]=f2bf(a[2]); r[3]=f2bf(a[3]);
  r[4]=f2bf(b[0]); r[5]=f2bf(b[1]); r[6]=f2bf(b[2]); r[7]=f2bf(b[3]);
  *((u16x8*)(out + (size_t)which * 8388608) + li) = r;
}

// --------------------------- fused weight cast+transpose x4: WT[n][k]=W[k][n]
__global__ __launch_bounds__(256) void castWT4_k(const float* __restrict__ w0,
                                                 const float* __restrict__ w1,
                                                 const float* __restrict__ w2,
                                                 const float* __restrict__ w3,
                                                 u16* __restrict__ WTb) {
  __shared__ u16 tile[64][72];
  int z = blockIdx.z;
  const float* W = z == 0 ? w0 : z == 1 ? w1 : z == 2 ? w2 : w3;
  u16* WT = WTb + (size_t)z * 1048576;
  int bx = blockIdx.x, by = blockIdx.y, t = threadIdx.x;
  for (int rr = 0; rr < 4; rr++) {
    int r = rr * 16 + (t >> 4);
    int c = (t & 15) * 4;
    float4 v = *(const float4*)(W + (size_t)(by * 64 + r) * 1024 + bx * 64 + c);
    tile[c + 0][r] = f2bf(v.x); tile[c + 1][r] = f2bf(v.y);
    tile[c + 2][r] = f2bf(v.z); tile[c + 3][r] = f2bf(v.w);
  }
  __syncthreads();
  for (int rr = 0; rr < 2; rr++) {
    int gid = rr * 256 + t;
    int r = gid >> 3, g = gid & 7;
    u16x8 v = *(const u16x8*)&tile[r][g * 8];
    *(u16x8*)(WT + (size_t)(bx * 64 + r) * 1024 + by * 64 + g * 8) = v;
  }
}

// --------------- all-ones flags per [kt:64 sk x qt:128 sq] tile, from mask
__global__ __launch_bounds__(256) void flags_k(const float* __restrict__ mask,
                                               int* __restrict__ flags) {
  __shared__ int ok_s;
  int t = threadIdx.x;
  if (t == 0) ok_s = 1;
  __syncthreads();
  int qt = blockIdx.x, kt = blockIdx.y, b = blockIdx.z;
  const float* base = mask + ((size_t)b * Sn + qt * 128) * Sn + kt * 64;
  int r = t >> 1, c0 = (t & 1) * 32;
  const float* p = base + (size_t)r * Sn + c0;
  bool ok = true;
  for (int i = 0; i < 8; i++) {
    float4 v = *(const float4*)(p + i * 4);
    ok = ok && (v.x == 1.0f) && (v.y == 1.0f) && (v.z == 1.0f) && (v.w == 1.0f);
  }
  if (!ok) atomicAnd(&ok_s, 0);
  __syncthreads();
  if (t == 0) flags[(b * 32 + kt) * 16 + qt] = ok_s;
}

// ---------------------------------------------------------------------------
// GEMM core: C[8192x1024] = A @ BT^T + bias. 128x128 tile, BK=64, 4 waves.
// mode 0: Q head-split bf16 * (0.125*log2e); 1: K head-split;
// mode 2: V -> vt[b][h][d][s]; mode 3: f32 flat out (+bias)
// ---------------------------------------------------------------------------
__device__ __forceinline__ void gemm_body(const u16* __restrict__ A,
                                          const u16* __restrict__ BT,
                                          const float* __restrict__ bias,
                                          void* __restrict__ outp, int mode,
                                          int nt, int mt, char* sm) {
  const int K = 1024;
  int m0 = mt * 128, n0 = nt * 128;
  int tid = threadIdx.x, w = tid >> 6, l = tid & 63, l15 = l & 15, l4 = l >> 4;
  int wm = w >> 1, wn = w & 1;

  size_t goff_a[4], goff_b[4];
  int lbase[4];
  for (int i = 0; i < 4; i++) {
    int gi = (w * 4 + i) * 64 + l;
    int row = gi >> 3, g = gi & 7;
    int gx = g ^ (row & 7);
    goff_a[i] = (size_t)(m0 + row) * K + gx * 8;
    goff_b[i] = (size_t)(n0 + row) * K + gx * 8;
    lbase[i] = (w * 4 + i) * 1024;
  }

  f32x4 acc[4][4] = {};
  for (int t = 0; t < 16; t++) {
    int k0 = t * 64;
    for (int i = 0; i < 4; i++) {
      GLDS16(A + goff_a[i] + k0, sm + lbase[i]);
      GLDS16(BT + goff_b[i] + k0, sm + 16384 + lbase[i]);
    }
    __syncthreads();
#pragma unroll
    for (int kk = 0; kk < 2; kk++) {
      int kb = kk * 64 + l4 * 16;
      bf16x8 af[4], bf[4];
#pragma unroll
      for (int mi = 0; mi < 4; mi++) {
        int row = wm * 64 + mi * 16 + l15;
        af[mi] = *(const bf16x8*)(sm + row * 128 + (kb ^ ((row & 7) << 4)));
      }
#pragma unroll
      for (int nj = 0; nj < 4; nj++) {
        int row = wn * 64 + nj * 16 + l15;
        bf[nj] = *(const bf16x8*)(sm + 16384 + row * 128 + (kb ^ ((row & 7) << 4)));
      }
#pragma unroll
      for (int mi = 0; mi < 4; mi++)
#pragma unroll
        for (int nj = 0; nj < 4; nj++)
          acc[mi][nj] = __builtin_amdgcn_mfma_f32_16x16x32_bf16(af[mi], bf[nj], acc[mi][nj], 0, 0, 0);
    }
    __syncthreads();
  }

  if (mode == 3) {
    float* out = (float*)outp;
#pragma unroll
    for (int mi = 0; mi < 4; mi++)
#pragma unroll
      for (int nj = 0; nj < 4; nj++)
#pragma unroll
        for (int r = 0; r < 4; r++) {
          int mg = m0 + wm * 64 + mi * 16 + l4 * 4 + r;
          int ng = n0 + wn * 64 + nj * 16 + l15;
          out[(size_t)mg * 1024 + ng] = acc[mi][nj][r] + bias[ng];
        }
  } else if (mode == 2) {
    u16* vt = (u16*)outp;
#pragma unroll
    for (int mi = 0; mi < 4; mi++)
#pragma unroll
      for (int nj = 0; nj < 4; nj++) {
        int ng = n0 + wn * 64 + nj * 16 + l15;
        int h = ng >> 6, d = ng & 63;
        int mgb = m0 + wm * 64 + mi * 16 + l4 * 4;
        int b = mgb >> 11, s = mgb & 2047;
        float bs = bias[ng];
        u16x4 pk;
#pragma unroll
        for (int r = 0; r < 4; r++) pk[r] = f2bf(acc[mi][nj][r] + bs);
        *(u16x4*)(vt + ((size_t)(b * Hn + h) * DHn + d) * Sn + s) = pk;
      }
  } else {
    u16* oh = (u16*)outp;
    float sc = (mode == 0) ? 0.18033688f : 1.0f;   // 0.125 * log2(e)
#pragma unroll
    for (int mi = 0; mi < 4; mi++)
#pragma unroll
      for (int nj = 0; nj < 4; nj++) {
        int ng = n0 + wn * 64 + nj * 16 + l15;
        int h = ng >> 6, d = ng & 63;
        float bs = bias[ng];
#pragma unroll
        for (int r = 0; r < 4; r++) {
          int mg = m0 + wm * 64 + mi * 16 + l4 * 4 + r;
          int b = mg >> 11, s = mg & 2047;
          oh[((size_t)(b * Hn + h) * Sn + s) * DHn + d] = f2bf((acc[mi][nj][r] + bs) * sc);
        }
      }
  }
}

// out-GEMM, 1D grid 512, XCD-chunked swizzle (chunk = 64)
__global__ __launch_bounds__(256) void gemmO_k(const u16* __restrict__ A,
                                               const u16* __restrict__ BT,
                                               const float* __restrict__ bias,
                                               float* __restrict__ outp) {
  __shared__ __align__(16) char sm[32768];
  int hw = blockIdx.x;
  int lg = (hw & 7) * 64 + (hw >> 3);
  int nt = lg & 7, mt = lg >> 3;
  gemm_body(A, BT, bias, (void*)outp, 3, nt, mt, sm);
}

// fused QKV projection, 1D grid 1536, XCD-chunked swizzle (chunk = 192)
__global__ __launch_bounds__(256) void gemm3_k(const u16* __restrict__ Ab,
                                               const u16* __restrict__ BTb,
                                               const float* __restrict__ b0,
                                               const float* __restrict__ b1,
                                               const float* __restrict__ b2,
                                               u16* __restrict__ outb) {
  __shared__ __align__(16) char sm[32768];
  int hw = blockIdx.x;
  int lg = (hw & 7) * 192 + (hw >> 3);
  int z = lg >> 9, r = lg & 511;
  int nt = r & 7, mt = r >> 3;
  const u16* A = Ab + (size_t)z * 8388608;
  const u16* BT = BTb + (size_t)z * 1048576;
  const float* bias = z == 0 ? b0 : z == 1 ? b1 : b2;
  u16* out = outb + (size_t)z * 8388608;
  gemm_body(A, BT, bias, (void*)out, z, nt, mt, sm);
}

// ---------------------------------------------------------------------------
// Attention pass 1: c[row] = log2( sum_k exp2(s'_k) ), s' = (q.k)/8*log2e.
// block=(qt,h,b) via XCD-chunk swizzle; 4 waves; KBLK=128 (2 x 64 halves);
// K double-buffered in 32KB LDS; no max tracking; one reduce per row at end.
// ---------------------------------------------------------------------------
__global__ __launch_bounds__(256) void pass1_k(
    const u16* __restrict__ qh, const u16* __restrict__ kh,
    const float* __restrict__ mask, const int* __restrict__ flags,
    float* __restrict__ cvec) {
  __shared__ __align__(16) char sm[32768];
  int hw = blockIdx.x;
  int lg = (hw & 7) * 128 + (hw >> 3);
  int qt = lg & 15, h = (lg >> 4) & 15, b = lg >> 8;
  int bh = b * Hn + h;
  int tid = threadIdx.x, w = tid >> 6, l = tid & 63, l15 = l & 15, l4 = l >> 4;

  const u16* Qg = qh + ((size_t)bh * Sn + qt * 128) * DHn;
  const u16* Kg = kh + (size_t)bh * Sn * DHn;
  const float* Mg = mask + (size_t)b * Sn * Sn + (size_t)(qt * 128) * Sn;

  u32 fl = (u32)__ballot(l < 32 && flags[(b * 32 + l) * 16 + qt] != 0);

  int srow[4], sgx8[4], sdst[4];
  for (int i = 0; i < 4; i++) {
    int gid = i * 256 + tid, row = gid >> 3, g = gid & 7;
    srow[i] = row; sgx8[i] = (g ^ (row & 7)) * 8; sdst[i] = gid * 16;
  }
#define STAGE_K128(t, buf)                                                     \
  for (int i = 0; i < 4; i++)                                                  \
    GLDS16(Kg + (size_t)((t) * 128 + srow[i]) * DHn + sgx8[i], sm + (buf) + sdst[i]);

  bf16x8 qf[2][2];
#pragma unroll
  for (int ni = 0; ni < 2; ni++)
#pragma unroll
    for (int kk = 0; kk < 2; kk++)
      qf[ni][kk] = *(const bf16x8*)(Qg + (size_t)(w * 32 + ni * 16 + l15) * DHn + kk * 32 + l4 * 8);

  float lsum[2] = {0.f, 0.f};

  STAGE_K128(0, 0);
  for (int t = 0; t < 16; t++) {
    int kcur = (t & 1) ? 16384 : 0;
    __syncthreads();
    if (t < 15) { int knxt = (t & 1) ? 0 : 16384; STAGE_K128(t + 1, knxt); }
#pragma unroll
    for (int h2 = 0; h2 < 2; h2++) {
      int kt = t * 2 + h2;
      f32x4 s[4][2] = {};
#pragma unroll
      for (int kk = 0; kk < 2; kk++) {
        int kb = kk * 64 + l4 * 16;
        bf16x8 a[4];
#pragma unroll
        for (int mi = 0; mi < 4; mi++) {
          int row = h2 * 64 + mi * 16 + l15;
          a[mi] = *(const bf16x8*)(sm + kcur + row * 128 + (kb ^ ((row & 7) << 4)));
        }
#pragma unroll
        for (int mi = 0; mi < 4; mi++)
#pragma unroll
          for (int ni = 0; ni < 2; ni++)
            s[mi][ni] = __builtin_amdgcn_mfma_f32_16x16x32_bf16(a[mi], qf[ni][kk], s[mi][ni], 0, 0, 0);
      }
      if (!((fl >> kt) & 1)) {
#pragma unroll
        for (int ni = 0; ni < 2; ni++) {
          const float* mrow = Mg + (size_t)(w * 32 + ni * 16 + l15) * Sn + kt * 64;
#pragma unroll
          for (int mi = 0; mi < 4; mi++) {
            f32x4 mv = *(const f32x4*)(mrow + mi * 16 + l4 * 4);
#pragma unroll
            for (int r = 0; r < 4; r++)
              s[mi][ni][r] = s[mi][ni][r] * mv[r] + MASK_NEG * (1.f - mv[r]);
          }
        }
      }
#pragma unroll
      for (int ni = 0; ni < 2; ni++)
#pragma unroll
        for (int mi = 0; mi < 4; mi++)
#pragma unroll
          for (int r = 0; r < 4; r++) lsum[ni] += __builtin_exp2f(s[mi][ni][r]);
    }
  }
#pragma unroll
  for (int ni = 0; ni < 2; ni++) {
    lsum[ni] += __shfl_xor(lsum[ni], 16);
    lsum[ni] += __shfl_xor(lsum[ni], 32);
  }
  if (l4 == 0) {
#pragma unroll
    for (int ni = 0; ni < 2; ni++)
      cvec[(size_t)bh * Sn + qt * 128 + w * 32 + ni * 16 + l15] = __builtin_log2f(lsum[ni]);
  }
}

// ---------------------------------------------------------------------------
// Attention pass 2: attn = exp2(s' - c) (normalized), ctx^T += V^T x P^T.
// KBLK=64, K/V double-buffered, 1 barrier/tile, P wave-private LDS.
// LDS: K0 8K | K1 8K | V0 8K | V1 8K | P 16K = 48KB.
// ---------------------------------------------------------------------------
#define K0_OFF 0
#define K1_OFF 8192
#define V0_OFF 16384
#define V1_OFF 24576
#define P_OFF  32768

__global__ __launch_bounds__(256) void pass2_k(
    const u16* __restrict__ qh, const u16* __restrict__ kh,
    const u16* __restrict__ vt, const float* __restrict__ mask,
    const int* __restrict__ flags, const float* __restrict__ cvec,
    float* __restrict__ attn, u16* __restrict__ ctxc) {
  __shared__ __align__(16) char sm[49152];
  int hw = blockIdx.x;
  int lg = (hw & 7) * 128 + (hw >> 3);
  int qt = lg & 15, h = (lg >> 4) & 15, b = lg >> 8;
  int bh = b * Hn + h;
  int tid = threadIdx.x, w = tid >> 6, l = tid & 63, l15 = l & 15, l4 = l >> 4;

  const u16* Qg = qh + ((size_t)bh * Sn + qt * 128) * DHn;
  const u16* Kg = kh + (size_t)bh * Sn * DHn;
  const u16* Vg = vt + (size_t)bh * DHn * Sn;
  const float* Mg = mask + (size_t)b * Sn * Sn + (size_t)(qt * 128) * Sn;

  u32 fl = (u32)__ballot(l < 32 && flags[(b * 32 + l) * 16 + qt] != 0);

  float cv[2];
#pragma unroll
  for (int ni = 0; ni < 2; ni++)
    cv[ni] = cvec[(size_t)bh * Sn + qt * 128 + w * 32 + ni * 16 + l15];

  int srow[2], sgx8[2], sdst[2];
  for (int i = 0; i < 2; i++) {
    int gid = i * 256 + tid, row = gid >> 3, g = gid & 7;
    srow[i] = row; sgx8[i] = (g ^ (row & 7)) * 8; sdst[i] = gid * 16;
  }
#define STAGE_K(t, buf)                                                        \
  for (int i = 0; i < 2; i++)                                                  \
    GLDS16(Kg + (size_t)((t) * 64 + srow[i]) * DHn + sgx8[i], sm + (buf) + sdst[i]);
#define STAGE_V(t, buf)                                                        \
  for (int i = 0; i < 2; i++)                                                  \
    GLDS16(Vg + (size_t)srow[i] * Sn + (t) * 64 + sgx8[i], sm + (buf) + sdst[i]);

  bf16x8 qf[2][2];
#pragma unroll
  for (int ni = 0; ni < 2; ni++)
#pragma unroll
    for (int kk = 0; kk < 2; kk++)
      qf[ni][kk] = *(const bf16x8*)(Qg + (size_t)(w * 32 + ni * 16 + l15) * DHn + kk * 32 + l4 * 8);

  f32x4 ctx[4][2] = {};
  STAGE_K(0, K0_OFF);
  STAGE_V(0, V0_OFF);
  for (int t = 0; t < 32; t++) {
    int kcur = (t & 1) ? K1_OFF : K0_OFF;
    int vcur = (t & 1) ? V1_OFF : V0_OFF;
    __syncthreads();
    if (t < 31) {
      int knxt = (t & 1) ? K0_OFF : K1_OFF;
      int vnxt = (t & 1) ? V0_OFF : V1_OFF;
      STAGE_K(t + 1, knxt);
      STAGE_V(t + 1, vnxt);
    }
    f32x4 s[4][2] = {};
#pragma unroll
    for (int kk = 0; kk < 2; kk++) {
      int kb = kk * 64 + l4 * 16;
      bf16x8 a[4];
#pragma unroll
      for (int mi = 0; mi < 4; mi++) {
        int row = mi * 16 + l15;
        a[mi] = *(const bf16x8*)(sm + kcur + row * 128 + (kb ^ ((row & 7) << 4)));
      }
#pragma unroll
      for (int mi = 0; mi < 4; mi++)
#pragma unroll
        for (int ni = 0; ni < 2; ni++)
          s[mi][ni] = __builtin_amdgcn_mfma_f32_16x16x32_bf16(a[mi], qf[ni][kk], s[mi][ni], 0, 0, 0);
    }
    if (!((fl >> t) & 1)) {
#pragma unroll
      for (int ni = 0; ni < 2; ni++) {
        const float* mrow = Mg + (size_t)(w * 32 + ni * 16 + l15) * Sn + t * 64;
#pragma unroll
        for (int mi = 0; mi < 4; mi++) {
          f32x4 mv = *(const f32x4*)(mrow + mi * 16 + l4 * 4);
#pragma unroll
          for (int r = 0; r < 4; r++)
            s[mi][ni][r] = s[mi][ni][r] * mv[r] + MASK_NEG * (1.f - mv[r]);
        }
      }
    }
    // s := exp2(s - c)  -> normalized attention weight
#pragma unroll
    for (int ni = 0; ni < 2; ni++)
#pragma unroll
      for (int mi = 0; mi < 4; mi++)
#pragma unroll
        for (int r = 0; r < 4; r++) s[mi][ni][r] = __builtin_exp2f(s[mi][ni][r] - cv[ni]);
    // attn store first (acks drain under P-pack + PV)
#pragma unroll
    for (int ni = 0; ni < 2; ni++) {
      float* arow = attn + ((size_t)bh * Sn + qt * 128 + w * 32 + ni * 16 + l15) * Sn + t * 64;
#pragma unroll
      for (int mi = 0; mi < 4; mi++)
        *(f32x4*)(arow + mi * 16 + l4 * 4) = s[mi][ni];
    }
    // P -> LDS (bf16, wave-private rows)
#pragma unroll
    for (int ni = 0; ni < 2; ni++) {
      int q = w * 32 + ni * 16 + l15;
#pragma unroll
      for (int mi = 0; mi < 4; mi++) {
        u16x4 pk;
#pragma unroll
        for (int r = 0; r < 4; r++) pk[r] = f2bf(s[mi][ni][r]);
        int kb = mi * 32 + l4 * 8;
        *(u16x4*)(sm + P_OFF + q * 128 + (kb ^ ((q & 7) << 4))) = pk;
      }
    }
    // PV: ctx^T += Vt x P^T
#pragma unroll
    for (int kk = 0; kk < 2; kk++) {
      int kb = kk * 64 + l4 * 16;
      bf16x8 av[4], bp[2];
#pragma unroll
      for (int mi = 0; mi < 4; mi++) {
        int row = mi * 16 + l15;
        av[mi] = *(const bf16x8*)(sm + vcur + row * 128 + (kb ^ ((row & 7) << 4)));
      }
#pragma unroll
      for (int ni = 0; ni < 2; ni++) {
        int q = w * 32 + ni * 16 + l15;
        bp[ni] = *(const bf16x8*)(sm + P_OFF + q * 128 + (kb ^ ((q & 7) << 4)));
      }
#pragma unroll
      for (int mi = 0; mi < 4; mi++)
#pragma unroll
        for (int ni = 0; ni < 2; ni++)
          ctx[mi][ni] = __builtin_amdgcn_mfma_f32_16x16x32_bf16(av[mi], bp[ni], ctx[mi][ni], 0, 0, 0);
    }
  }

  // ctx epilogue (already normalized): bf16 pack, LDS, coalesced store
#pragma unroll
  for (int ni = 0; ni < 2; ni++) {
    int q = w * 32 + ni * 16 + l15;
#pragma unroll
    for (int mi = 0; mi < 4; mi++) {
      u16x4 ck;
#pragma unroll
      for (int r = 0; r < 4; r++) ck[r] = f2bf(ctx[mi][ni][r]);
      int db = mi * 32 + l4 * 8;
      *(u16x4*)(sm + P_OFF + q * 128 + (db ^ ((q & 7) << 4))) = ck;
    }
  }
  __syncthreads();
  {
    int q = tid >> 1, hf = tid & 1;
    u16* dst = ctxc + ((size_t)b * Sn + qt * 128 + q) * Dn + h * DHn + hf * 32;
#pragma unroll
    for (int c4 = 0; c4 < 4; c4++) {
      int db = hf * 64 + c4 * 16;
      i32x4 v = *(const i32x4*)(sm + P_OFF + q * 128 + (db ^ ((q & 7) << 4)));
      *(i32x4*)(dst + c4 * 8) = v;
    }
  }
}

// ---------------------------------------------------------------------------
extern "C" void kernel_launch(void* const* d_in, const int* in_sizes, int n_in,
                              void* d_out, int out_size, void* d_ws, size_t ws_size,
                              hipStream_t stream) {
  const float* v_f  = (const float*)d_in[0];
  const float* k_f  = (const float*)d_in[1];
  const float* q_f  = (const float*)d_in[2];
  const float* mask = (const float*)d_in[3];
  const float* wq_w = (const float*)d_in[4];
  const float* wq_b = (const float*)d_in[5];
  const float* wk_w = (const float*)d_in[6];
  const float* wk_b = (const float*)d_in[7];
  const float* wv_w = (const float*)d_in[8];
  const float* wv_b = (const float*)d_in[9];
  const float* wo_w = (const float*)d_in[10];
  const float* wo_b = (const float*)d_in[11];

  char* ws = (char*)d_ws;
  u16*   qbf  = (u16*)(ws + 0);             // q,k,v bf16 slabs (contig)
  u16*   wT   = (u16*)(ws + 50331648);      // wqT,wkT,wvT,woT (contig, 2MB ea)
  u16*   woT  = (u16*)(ws + 56623104);
  u16*   qhp  = (u16*)(ws + 58720256);      // Qh, Kh, Vt slabs (contig, 16MB ea)
  u16*   khp  = (u16*)(ws + 75497472);
  u16*   vtp  = (u16*)(ws + 92274688);
  u16*   ctxc = (u16*)(ws + 109051904);
  float* cvec = (float*)(ws + 125829120);   // 512 KB
  int*   flg  = (int*)(ws + 126353408);

  float* out  = (float*)d_out;
  float* attn = out + (size_t)Bn * Sn * Dn;

  cast3_k<<<12288, 256, 0, stream>>>(q_f, k_f, v_f, qbf);
  castWT4_k<<<dim3(16, 16, 4), 256, 0, stream>>>(wq_w, wk_w, wv_w, wo_w, wT);
  flags_k<<<dim3(16, 32, 4), 256, 0, stream>>>(mask, flg);

  gemm3_k<<<1536, 256, 0, stream>>>(qbf, wT, wq_b, wk_b, wv_b, qhp);

  pass1_k<<<1024, 256, 0, stream>>>(qhp, khp, mask, flg, cvec);
  pass2_k<<<1024, 256, 0, stream>>>(qhp, khp, vtp, mask, flg, cvec, attn, ctxc);

  gemmO_k<<<512, 256, 0, stream>>>(ctxc, woT, wo_b, out);
}

// Round 5
// 564.856 us; speedup vs baseline: 1.1533x; 1.1533x over previous
//
#include <hip/hip_runtime.h>

// ---------------------------------------------------------------------------
// CustomizedMultiHeadAttention: B=4 S=2048 D=1024 H=16 DH=64
// out [B,S,D] f32  +  attn_weights [B,H,S,S] f32, concat in d_out.
// v5: merged prep (cast3+castWT+flags, 1 launch); merged attention kernel
//     (phase A: base-2 lsum, KBLK=128; phase B: normalized stores + PV) so
//     co-resident blocks overlap A(MFMA) with B(store-BW); nontemporal
//     stores for final outputs. 4 launches total.
// ---------------------------------------------------------------------------

typedef unsigned short u16;
typedef unsigned int   u32;
typedef u16   u16x4  __attribute__((ext_vector_type(4)));
typedef u16   u16x8  __attribute__((ext_vector_type(8)));
typedef int   i32x4  __attribute__((ext_vector_type(4)));
typedef float f32x4  __attribute__((ext_vector_type(4)));
typedef __bf16 bf16x8 __attribute__((ext_vector_type(8)));

#define GLDS16(gp, lp)                                                         \
  __builtin_amdgcn_global_load_lds(                                            \
      (const __attribute__((address_space(1))) void*)(gp),                     \
      (__attribute__((address_space(3))) void*)(lp), 16, 0, 0)

__device__ __forceinline__ u16 f2bf(float x) {
  __bf16 h = (__bf16)x;
  union { __bf16 h; u16 u; } c; c.h = h; return c.u;
}
__device__ __forceinline__ void nt_store4(float* p, f32x4 v) {
  __builtin_nontemporal_store(v, (f32x4*)p);
}

static const int Bn = 4, Sn = 2048, Dn = 1024, Hn = 16, DHn = 64;
#define MASK_NEG (-1442695.0f)   /* -1e6 * log2(e) */

// ---------------------------------------------------------------------------
// prep: blocks [0,12288) cast q,k,v -> bf16; [12288,13312) weight cast+T;
//       [13312,15360) mask all-ones flags per [64 sk x 128 sq] tile.
// ---------------------------------------------------------------------------
__global__ __launch_bounds__(256) void prep_k(
    const float* __restrict__ q, const float* __restrict__ k,
    const float* __restrict__ v, const float* __restrict__ mask,
    const float* __restrict__ w0, const float* __restrict__ w1,
    const float* __restrict__ w2, const float* __restrict__ w3,
    u16* __restrict__ qkv, u16* __restrict__ WTb, int* __restrict__ flags) {
  __shared__ __align__(16) u16 tile[64][72];
  __shared__ int ok_s;
  int bid = blockIdx.x, t = threadIdx.x;

  if (bid < 12288) {                      // ---- cast q,k,v
    int which = bid >> 12;
    size_t li = (size_t)(bid & 4095) * 256 + t;
    const float* src = which == 0 ? q : which == 1 ? k : v;
    const f32x4* p = (const f32x4*)src + li * 2;
    f32x4 a = p[0], b = p[1];
    u16x8 r;
    r[0]=f2bf(a[0]); r[1]=f2bf(a[1]); r[2]=f2bf(a[2]); r[3]=f2bf(a[3]);
    r[4]=f2bf(b[0]); r[5]=f2bf(b[1]); r[6]=f2bf(b[2]); r[7]=f2bf(b[3]);
    *((u16x8*)(qkv + (size_t)which * 8388608) + li) = r;
  } else if (bid < 13312) {               // ---- weight cast + transpose
    int i = bid - 12288;
    int z = i >> 8, rem = i & 255, bx = rem & 15, by = rem >> 4;
    const float* W = z == 0 ? w0 : z == 1 ? w1 : z == 2 ? w2 : w3;
    u16* WT = WTb + (size_t)z * 1048576;
    for (int rr = 0; rr < 4; rr++) {
      int r = rr * 16 + (t >> 4);
      int c = (t & 15) * 4;
      float4 vv = *(const float4*)(W + (size_t)(by * 64 + r) * 1024 + bx * 64 + c);
      tile[c + 0][r] = f2bf(vv.x); tile[c + 1][r] = f2bf(vv.y);
      tile[c + 2][r] = f2bf(vv.z); tile[c + 3][r] = f2bf(vv.w);
    }
    __syncthreads();
    for (int rr = 0; rr < 2; rr++) {
      int gid = rr * 256 + t;
      int r = gid >> 3, g = gid & 7;
      u16x8 vv = *(const u16x8*)&tile[r][g * 8];
      *(u16x8*)(WT + (size_t)(bx * 64 + r) * 1024 + by * 64 + g * 8) = vv;
    }
  } else {                                // ---- mask flags
    int i = bid - 13312;
    int qt = i & 15, kt = (i >> 4) & 31, b = i >> 9;
    if (t == 0) ok_s = 1;
    __syncthreads();
    const float* base = mask + ((size_t)b * Sn + qt * 128) * Sn + kt * 64;
    int r = t >> 1, c0 = (t & 1) * 32;
    const float* p = base + (size_t)r * Sn + c0;
    bool ok = true;
    for (int j = 0; j < 8; j++) {
      float4 vv = *(const float4*)(p + j * 4);
      ok = ok && (vv.x == 1.0f) && (vv.y == 1.0f) && (vv.z == 1.0f) && (vv.w == 1.0f);
    }
    if (!ok) atomicAnd(&ok_s, 0);
    __syncthreads();
    if (t == 0) flags[(b * 32 + kt) * 16 + qt] = ok_s;
  }
}

// ---------------------------------------------------------------------------
// GEMM core: C[8192x1024] = A @ BT^T + bias. 128x128 tile, BK=64, 4 waves.
// mode 0: Q head-split bf16 * (0.125*log2e); 1: K head-split;
// mode 2: V -> vt[b][h][d][s]; mode 3: f32 flat out (+bias, nontemporal)
// ---------------------------------------------------------------------------
__device__ __forceinline__ void gemm_body(const u16* __restrict__ A,
                                          const u16* __restrict__ BT,
                                          const float* __restrict__ bias,
                                          void* __restrict__ outp, int mode,
                                          int nt, int mt, char* sm) {
  const int K = 1024;
  int m0 = mt * 128, n0 = nt * 128;
  int tid = threadIdx.x, w = tid >> 6, l = tid & 63, l15 = l & 15, l4 = l >> 4;
  int wm = w >> 1, wn = w & 1;

  size_t goff_a[4], goff_b[4];
  int lbase[4];
  for (int i = 0; i < 4; i++) {
    int gi = (w * 4 + i) * 64 + l;
    int row = gi >> 3, g = gi & 7;
    int gx = g ^ (row & 7);
    goff_a[i] = (size_t)(m0 + row) * K + gx * 8;
    goff_b[i] = (size_t)(n0 + row) * K + gx * 8;
    lbase[i] = (w * 4 + i) * 1024;
  }

  f32x4 acc[4][4] = {};
  for (int t = 0; t < 16; t++) {
    int k0 = t * 64;
    for (int i = 0; i < 4; i++) {
      GLDS16(A + goff_a[i] + k0, sm + lbase[i]);
      GLDS16(BT + goff_b[i] + k0, sm + 16384 + lbase[i]);
    }
    __syncthreads();
#pragma unroll
    for (int kk = 0; kk < 2; kk++) {
      int kb = kk * 64 + l4 * 16;
      bf16x8 af[4], bf[4];
#pragma unroll
      for (int mi = 0; mi < 4; mi++) {
        int row = wm * 64 + mi * 16 + l15;
        af[mi] = *(const bf16x8*)(sm + row * 128 + (kb ^ ((row & 7) << 4)));
      }
#pragma unroll
      for (int nj = 0; nj < 4; nj++) {
        int row = wn * 64 + nj * 16 + l15;
        bf[nj] = *(const bf16x8*)(sm + 16384 + row * 128 + (kb ^ ((row & 7) << 4)));
      }
#pragma unroll
      for (int mi = 0; mi < 4; mi++)
#pragma unroll
        for (int nj = 0; nj < 4; nj++)
          acc[mi][nj] = __builtin_amdgcn_mfma_f32_16x16x32_bf16(af[mi], bf[nj], acc[mi][nj], 0, 0, 0);
    }
    __syncthreads();
  }

  if (mode == 3) {
    float* out = (float*)outp;
#pragma unroll
    for (int mi = 0; mi < 4; mi++)
#pragma unroll
      for (int nj = 0; nj < 4; nj++)
#pragma unroll
        for (int r = 0; r < 4; r++) {
          int mg = m0 + wm * 64 + mi * 16 + l4 * 4 + r;
          int ng = n0 + wn * 64 + nj * 16 + l15;
          __builtin_nontemporal_store(acc[mi][nj][r] + bias[ng],
                                      out + (size_t)mg * 1024 + ng);
        }
  } else if (mode == 2) {
    u16* vt = (u16*)outp;
#pragma unroll
    for (int mi = 0; mi < 4; mi++)
#pragma unroll
      for (int nj = 0; nj < 4; nj++) {
        int ng = n0 + wn * 64 + nj * 16 + l15;
        int h = ng >> 6, d = ng & 63;
        int mgb = m0 + wm * 64 + mi * 16 + l4 * 4;
        int b = mgb >> 11, s = mgb & 2047;
        float bs = bias[ng];
        u16x4 pk;
#pragma unroll
        for (int r = 0; r < 4; r++) pk[r] = f2bf(acc[mi][nj][r] + bs);
        *(u16x4*)(vt + ((size_t)(b * Hn + h) * DHn + d) * Sn + s) = pk;
      }
  } else {
    u16* oh = (u16*)outp;
    float sc = (mode == 0) ? 0.18033688f : 1.0f;   // 0.125 * log2(e)
#pragma unroll
    for (int mi = 0; mi < 4; mi++)
#pragma unroll
      for (int nj = 0; nj < 4; nj++) {
        int ng = n0 + wn * 64 + nj * 16 + l15;
        int h = ng >> 6, d = ng & 63;
        float bs = bias[ng];
#pragma unroll
        for (int r = 0; r < 4; r++) {
          int mg = m0 + wm * 64 + mi * 16 + l4 * 4 + r;
          int b = mg >> 11, s = mg & 2047;
          oh[((size_t)(b * Hn + h) * Sn + s) * DHn + d] = f2bf((acc[mi][nj][r] + bs) * sc);
        }
      }
  }
}

// out-GEMM, 1D grid 512, XCD-chunked swizzle (chunk = 64)
__global__ __launch_bounds__(256) void gemmO_k(const u16* __restrict__ A,
                                               const u16* __restrict__ BT,
                                               const float* __restrict__ bias,
                                               float* __restrict__ outp) {
  __shared__ __align__(16) char sm[32768];
  int hw = blockIdx.x;
  int lg = (hw & 7) * 64 + (hw >> 3);
  int nt = lg & 7, mt = lg >> 3;
  gemm_body(A, BT, bias, (void*)outp, 3, nt, mt, sm);
}

// fused QKV projection, 1D grid 1536, XCD-chunked swizzle (chunk = 192)
__global__ __launch_bounds__(256) void gemm3_k(const u16* __restrict__ Ab,
                                               const u16* __restrict__ BTb,
                                               const float* __restrict__ b0,
                                               const float* __restrict__ b1,
                                               const float* __restrict__ b2,
                                               u16* __restrict__ outb) {
  __shared__ __align__(16) char sm[32768];
  int hw = blockIdx.x;
  int lg = (hw & 7) * 192 + (hw >> 3);
  int z = lg >> 9, r = lg & 511;
  int nt = r & 7, mt = r >> 3;
  const u16* A = Ab + (size_t)z * 8388608;
  const u16* BT = BTb + (size_t)z * 1048576;
  const float* bias = z == 0 ? b0 : z == 1 ? b1 : b2;
  u16* out = outb + (size_t)z * 8388608;
  gemm_body(A, BT, bias, (void*)out, z, nt, mt, sm);
}

// ---------------------------------------------------------------------------
// Merged attention. 1D grid 1024, XCD-chunked (chunk=128). 4 waves.
// Phase A: c[row] = log2(sum_k exp2(s')) with KBLK=128, K dbuf in 32KB LDS,
//          no max tracking, one shfl-reduce per row at the end (c in regs).
// Phase B: attn = exp2(s'-c) stored nontemporal (normalized), ctx^T += VtxP^T.
// LDS: phase A [0,32K) = 2x16KB K buffers; phase B K0|K1|V0|V1|P = 48KB.
// ---------------------------------------------------------------------------
#define K0_OFF 0
#define K1_OFF 8192
#define V0_OFF 16384
#define V1_OFF 24576
#define P_OFF  32768

__global__ __launch_bounds__(256) void attn_k(
    const u16* __restrict__ qh, const u16* __restrict__ kh,
    const u16* __restrict__ vt, const float* __restrict__ mask,
    const int* __restrict__ flags, float* __restrict__ attn,
    u16* __restrict__ ctxc) {
  __shared__ __align__(16) char sm[49152];
  int hw = blockIdx.x;
  int lg = (hw & 7) * 128 + (hw >> 3);
  int qt = lg & 15, h = (lg >> 4) & 15, b = lg >> 8;
  int bh = b * Hn + h;
  int tid = threadIdx.x, w = tid >> 6, l = tid & 63, l15 = l & 15, l4 = l >> 4;

  const u16* Qg = qh + ((size_t)bh * Sn + qt * 128) * DHn;
  const u16* Kg = kh + (size_t)bh * Sn * DHn;
  const u16* Vg = vt + (size_t)bh * DHn * Sn;
  const float* Mg = mask + (size_t)b * Sn * Sn + (size_t)(qt * 128) * Sn;

  u32 fl = (u32)__ballot(l < 32 && flags[(b * 32 + l) * 16 + qt] != 0);

  // staging source offsets (pre-swizzled granule)
  int srowA[4], sgxA[4], sdstA[4];
  for (int i = 0; i < 4; i++) {
    int gid = i * 256 + tid, row = gid >> 3, g = gid & 7;
    srowA[i] = row; sgxA[i] = (g ^ (row & 7)) * 8; sdstA[i] = gid * 16;
  }
#define STAGE_KA(t, buf)                                                       \
  for (int i = 0; i < 4; i++)                                                  \
    GLDS16(Kg + (size_t)((t) * 128 + srowA[i]) * DHn + sgxA[i], sm + (buf) + sdstA[i]);
#define STAGE_K(t, buf)                                                        \
  for (int i = 0; i < 2; i++)                                                  \
    GLDS16(Kg + (size_t)((t) * 64 + srowA[i]) * DHn + sgxA[i], sm + (buf) + sdstA[i]);
#define STAGE_V(t, buf)                                                        \
  for (int i = 0; i < 2; i++)                                                  \
    GLDS16(Vg + (size_t)srowA[i] * Sn + (t) * 64 + sgxA[i], sm + (buf) + sdstA[i]);

  // Q fragments in registers (B-operand: col=sq(l15), k=d(l4*8+j))
  bf16x8 qf[2][2];
#pragma unroll
  for (int ni = 0; ni < 2; ni++)
#pragma unroll
    for (int kk = 0; kk < 2; kk++)
      qf[ni][kk] = *(const bf16x8*)(Qg + (size_t)(w * 32 + ni * 16 + l15) * DHn + kk * 32 + l4 * 8);

  // ---------------- phase A: lsum (no max tracking) ----------------
  float lsum[2] = {0.f, 0.f};
  STAGE_KA(0, 0);
  for (int t = 0; t < 16; t++) {
    int kcur = (t & 1) ? 16384 : 0;
    __syncthreads();
    if (t < 15) { int knxt = (t & 1) ? 0 : 16384; STAGE_KA(t + 1, knxt); }
#pragma unroll
    for (int h2 = 0; h2 < 2; h2++) {
      int kt = t * 2 + h2;
      f32x4 s[4][2] = {};
#pragma unroll
      for (int kk = 0; kk < 2; kk++) {
        int kb = kk * 64 + l4 * 16;
        bf16x8 a[4];
#pragma unroll
        for (int mi = 0; mi < 4; mi++) {
          int row = h2 * 64 + mi * 16 + l15;
          a[mi] = *(const bf16x8*)(sm + kcur + row * 128 + (kb ^ ((row & 7) << 4)));
        }
#pragma unroll
        for (int mi = 0; mi < 4; mi++)
#pragma unroll
          for (int ni = 0; ni < 2; ni++)
            s[mi][ni] = __builtin_amdgcn_mfma_f32_16x16x32_bf16(a[mi], qf[ni][kk], s[mi][ni], 0, 0, 0);
      }
      if (!((fl >> kt) & 1)) {
#pragma unroll
        for (int ni = 0; ni < 2; ni++) {
          const float* mrow = Mg + (size_t)(w * 32 + ni * 16 + l15) * Sn + kt * 64;
#pragma unroll
          for (int mi = 0; mi < 4; mi++) {
            f32x4 mv = *(const f32x4*)(mrow + mi * 16 + l4 * 4);
#pragma unroll
            for (int r = 0; r < 4; r++)
              s[mi][ni][r] = s[mi][ni][r] * mv[r] + MASK_NEG * (1.f - mv[r]);
          }
        }
      }
#pragma unroll
      for (int ni = 0; ni < 2; ni++)
#pragma unroll
        for (int mi = 0; mi < 4; mi++)
#pragma unroll
          for (int r = 0; r < 4; r++) lsum[ni] += __builtin_exp2f(s[mi][ni][r]);
    }
  }
  float cv[2];
#pragma unroll
  for (int ni = 0; ni < 2; ni++) {
    lsum[ni] += __shfl_xor(lsum[ni], 16);
    lsum[ni] += __shfl_xor(lsum[ni], 32);
    cv[ni] = __builtin_log2f(lsum[ni]);
  }

  // ---------------- phase B: normalized stores + PV ----------------
  __syncthreads();                         // phase A LDS reads complete
  f32x4 ctx[4][2] = {};
  STAGE_K(0, K0_OFF);
  STAGE_V(0, V0_OFF);
  for (int t = 0; t < 32; t++) {
    int kcur = (t & 1) ? K1_OFF : K0_OFF;
    int vcur = (t & 1) ? V1_OFF : V0_OFF;
    __syncthreads();
    if (t < 31) {
      int knxt = (t & 1) ? K0_OFF : K1_OFF;
      int vnxt = (t & 1) ? V0_OFF : V1_OFF;
      STAGE_K(t + 1, knxt);
      STAGE_V(t + 1, vnxt);
    }
    f32x4 s[4][2] = {};
#pragma unroll
    for (int kk = 0; kk < 2; kk++) {
      int kb = kk * 64 + l4 * 16;
      bf16x8 a[4];
#pragma unroll
      for (int mi = 0; mi < 4; mi++) {
        int row = mi * 16 + l15;
        a[mi] = *(const bf16x8*)(sm + kcur + row * 128 + (kb ^ ((row & 7) << 4)));
      }
#pragma unroll
      for (int mi = 0; mi < 4; mi++)
#pragma unroll
        for (int ni = 0; ni < 2; ni++)
          s[mi][ni] = __builtin_amdgcn_mfma_f32_16x16x32_bf16(a[mi], qf[ni][kk], s[mi][ni], 0, 0, 0);
    }
    if (!((fl >> t) & 1)) {
#pragma unroll
      for (int ni = 0; ni < 2; ni++) {
        const float* mrow = Mg + (size_t)(w * 32 + ni * 16 + l15) * Sn + t * 64;
#pragma unroll
        for (int mi = 0; mi < 4; mi++) {
          f32x4 mv = *(const f32x4*)(mrow + mi * 16 + l4 * 4);
#pragma unroll
          for (int r = 0; r < 4; r++)
            s[mi][ni][r] = s[mi][ni][r] * mv[r] + MASK_NEG * (1.f - mv[r]);
        }
      }
    }
    // s := exp2(s - c)  -> normalized attention weight
#pragma unroll
    for (int ni = 0; ni < 2; ni++)
#pragma unroll
      for (int mi = 0; mi < 4; mi++)
#pragma unroll
        for (int r = 0; r < 4; r++) s[mi][ni][r] = __builtin_exp2f(s[mi][ni][r] - cv[ni]);
    // attn store (nontemporal; acks drain under P-pack + PV)
#pragma unroll
    for (int ni = 0; ni < 2; ni++) {
      float* arow = attn + ((size_t)bh * Sn + qt * 128 + w * 32 + ni * 16 + l15) * Sn + t * 64;
#pragma unroll
      for (int mi = 0; mi < 4; mi++)
        nt_store4(arow + mi * 16 + l4 * 4, s[mi][ni]);
    }
    // P -> LDS (bf16, wave-private rows)
#pragma unroll
    for (int ni = 0; ni < 2; ni++) {
      int q = w * 32 + ni * 16 + l15;
#pragma unroll
      for (int mi = 0; mi < 4; mi++) {
        u16x4 pk;
#pragma unroll
        for (int r = 0; r < 4; r++) pk[r] = f2bf(s[mi][ni][r]);
        int kb = mi * 32 + l4 * 8;
        *(u16x4*)(sm + P_OFF + q * 128 + (kb ^ ((q & 7) << 4))) = pk;
      }
    }
    // PV: ctx^T += Vt x P^T (bp reads own wave's P rows only)
#pragma unroll
    for (int kk = 0; kk < 2; kk++) {
      int kb = kk * 64 + l4 * 16;
      bf16x8 av[4], bp[2];
#pragma unroll
      for (int mi = 0; mi < 4; mi++) {
        int row = mi * 16 + l15;
        av[mi] = *(const bf16x8*)(sm + vcur + row * 128 + (kb ^ ((row & 7) << 4)));
      }
#pragma unroll
      for (int ni = 0; ni < 2; ni++) {
        int q = w * 32 + ni * 16 + l15;
        bp[ni] = *(const bf16x8*)(sm + P_OFF + q * 128 + (kb ^ ((q & 7) << 4)));
      }
#pragma unroll
      for (int mi = 0; mi < 4; mi++)
#pragma unroll
        for (int ni = 0; ni < 2; ni++)
          ctx[mi][ni] = __builtin_amdgcn_mfma_f32_16x16x32_bf16(av[mi], bp[ni], ctx[mi][ni], 0, 0, 0);
    }
  }

  // ctx epilogue (already normalized): bf16 pack, LDS, coalesced store
#pragma unroll
  for (int ni = 0; ni < 2; ni++) {
    int q = w * 32 + ni * 16 + l15;
#pragma unroll
    for (int mi = 0; mi < 4; mi++) {
      u16x4 ck;
#pragma unroll
      for (int r = 0; r < 4; r++) ck[r] = f2bf(ctx[mi][ni][r]);
      int db = mi * 32 + l4 * 8;
      *(u16x4*)(sm + P_OFF + q * 128 + (db ^ ((q & 7) << 4))) = ck;
    }
  }
  __syncthreads();
  {
    int q = tid >> 1, hf = tid & 1;
    u16* dst = ctxc + ((size_t)b * Sn + qt * 128 + q) * Dn + h * DHn + hf * 32;
#pragma unroll
    for (int c4 = 0; c4 < 4; c4++) {
      int db = hf * 64 + c4 * 16;
      i32x4 v = *(const i32x4*)(sm + P_OFF + q * 128 + (db ^ ((q & 7) << 4)));
      *(i32x4*)(dst + c4 * 8) = v;
    }
  }
}

// ---------------------------------------------------------------------------
extern "C" void kernel_launch(void* const* d_in, const int* in_sizes, int n_in,
                              void* d_out, int out_size, void* d_ws, size_t ws_size,
                              hipStream_t stream) {
  const float* v_f  = (const float*)d_in[0];
  const float* k_f  = (const float*)d_in[1];
  const float* q_f  = (const float*)d_in[2];
  const float* mask = (const float*)d_in[3];
  const float* wq_w = (const float*)d_in[4];
  const float* wq_b = (const float*)d_in[5];
  const float* wk_w = (const float*)d_in[6];
  const float* wk_b = (const float*)d_in[7];
  const float* wv_w = (const float*)d_in[8];
  const float* wv_b = (const float*)d_in[9];
  const float* wo_w = (const float*)d_in[10];
  const float* wo_b = (const float*)d_in[11];

  char* ws = (char*)d_ws;
  u16*   qbf  = (u16*)(ws + 0);             // q,k,v bf16 slabs (contig)
  u16*   wT   = (u16*)(ws + 50331648);      // wqT,wkT,wvT,woT (contig, 2MB ea)
  u16*   woT  = (u16*)(ws + 56623104);
  u16*   qhp  = (u16*)(ws + 58720256);      // Qh, Kh, Vt slabs (contig, 16MB ea)
  u16*   khp  = (u16*)(ws + 75497472);
  u16*   vtp  = (u16*)(ws + 92274688);
  u16*   ctxc = (u16*)(ws + 109051904);
  int*   flg  = (int*)(ws + 125829120);

  float* out  = (float*)d_out;
  float* attn = out + (size_t)Bn * Sn * Dn;

  prep_k<<<15360, 256, 0, stream>>>(q_f, k_f, v_f, mask,
                                    wq_w, wk_w, wv_w, wo_w, qbf, wT, flg);
  gemm3_k<<<1536, 256, 0, stream>>>(qbf, wT, wq_b, wk_b, wv_b, qhp);
  attn_k<<<1024, 256, 0, stream>>>(qhp, khp, vtp, mask, flg, attn, ctxc);
  gemmO_k<<<512, 256, 0, stream>>>(ctxc, woT, wo_b, out);
}